// Round 8
// baseline (1516.294 us; speedup 1.0000x reference)
//
#include <hip/hip_runtime.h>
#include <hip/hip_bf16.h>

#define NBLK 50
#define HID  16
#define BATCH 16
#define HH 128
#define WW 128
#define PH 136
#define PW 136
#define NCH 2
#define PXS 32                 // shorts per pixel (64 B)
#define ROWE (PW*PXS)          // 4352 shorts = 8704 B per (row, chunk)
#define ROWP (ROWE+256)        // +512 B pad: wave3's P2 over-read stays in-bounds
#define TAPE 512               // elements per A tap-fragment (64 lanes * 8)

typedef __attribute__((ext_vector_type(8))) short short8;
typedef __attribute__((ext_vector_type(4))) float floatx4;
typedef __attribute__((ext_vector_type(4))) int   i32x4;

static __device__ __forceinline__ unsigned short f2bf(float f) {
    unsigned int u = __float_as_uint(f);
    unsigned int r = (u + 0x7fffu + ((u >> 16) & 1u)) >> 16;
    return (unsigned short)r;
}

// Bank-conflict swizzle: 16B unit u = px*4+kg stored at u ^ ((px>>1)&7).
// (Kept from R2: feats layout, init/zero/epilogue all use it; the P-reads
// below are contiguous either way.) Buffer bases are multiples of 8 units,
// so the local swizzle equals the global one.
static __device__ __forceinline__ int swz(int px, int kg) {
    return (px * 4 + kg) ^ ((px >> 1) & 7);
}

// B-fragment synthesis via DPP row shifts (16-lane rows == our n-groups).
// Canonical GCN semantics: row_shr:N -> dest[i]=src[i-N]; row_shl:N ->
// dest[i]=src[i+N]; invalid lanes 0-filled (bound_ctrl, old=0). Valid-lane
// sets of the two shifts are disjoint and cover the row, so OR merges:
//   frag_kx[n] = lo[n+kx] (n<=15-kx)  |  hi[n+kx-16] (n>=16-kx)
// which is exactly strip[n+kx] when lo=strip[n+0..15], hi=strip[n+16..31].
template<int KX>
static __device__ __forceinline__ short8 mkfrag(short8 lo, short8 hi) {
    if constexpr (KX == 0) {
        return lo;
    } else {
        i32x4 a = __builtin_bit_cast(i32x4, lo);
        i32x4 b = __builtin_bit_cast(i32x4, hi);
        i32x4 r;
        #pragma unroll
        for (int j = 0; j < 4; ++j)
            r[j] = __builtin_amdgcn_update_dpp(0, a[j], 0x100 + KX,        0xf, 0xf, true)
                 | __builtin_amdgcn_update_dpp(0, b[j], 0x110 + (16 - KX), 0xf, 0xf, true);
        return __builtin_bit_cast(short8, r);
    }
}

#define GLD16(gp, lp) __builtin_amdgcn_global_load_lds( \
    (__attribute__((address_space(1))) void*)(void*)(gp), \
    (__attribute__((address_space(3))) void*)(lp), 16, 0, 0)

// Stage one feats row-chunk (8704 B contiguous) into LDS.
static __device__ __forceinline__ void stage_row(const unsigned short* g, unsigned short* l, int tid) {
    const char* gb = (const char*)g;
    char* lb = (char*)l;
    GLD16(gb + tid * 16,        lb + (tid & ~63) * 16);
    GLD16(gb + 4096 + tid * 16, lb + 4096 + (tid & ~63) * 16);
    if (tid < 32) GLD16(gb + 8192 + tid * 16, lb + 8192 + (tid & ~63) * 16);
}

// Pack w1 (fp32 [50][16][51][9][9]) into A-fragment order:
// wbuf[blk][chunk][tap][lane][8], lane: m=lane&15 (hidden ch), k=(lane>>4)*8+j.
// Zero for c>blk (K-padding + write-channel read-safety).
__global__ void prep_w(const float* __restrict__ w1, unsigned short* __restrict__ wbuf) {
    int idx = blockIdx.x * 256 + threadIdx.x;
    const int total = NBLK * NCH * 81 * TAPE;
    if (idx >= total) return;
    int e    = idx & 7;
    int lane = (idx >> 3) & 63;
    int tap  = (idx >> 9) % 81;
    int bc   = idx / (81 * TAPE);
    int ch   = bc & 1, blk = bc >> 1;
    int hc   = lane & 15;
    int c    = ch * 32 + (lane >> 4) * 8 + e;
    float v = 0.f;
    if (c <= blk) v = w1[(((size_t)blk * HID + hc) * (1 + NBLK) + c) * 81 + tap];
    wbuf[idx] = f2bf(v);
}

// Zero only the halo pixels (swizzled unit addresses). Unwritten interior
// channels are safe: weight columns zeroed in wbuf, 0xAA-poison bf16 finite.
__global__ void zero_halo(unsigned short* __restrict__ feats) {
    int t = blockIdx.x * 256 + threadIdx.x;
    const int PPX = 2112;                 // halo px per (b, chunk)
    const int TOT = BATCH * NCH * PPX * 4;
    if (t >= TOT) return;
    int w    = t & 3;
    int rest = t >> 2;
    int p    = rest % PPX;
    int ch   = (rest / PPX) % NCH;
    int b    = rest / (PPX * NCH);
    int row, px;
    if (p < 1088) {                        // rows 0-3, 132-135 (full)
        int r4 = p / 136; px = p % 136;
        row = (r4 < 4) ? r4 : r4 + 128;
    } else {                               // rows 4-131, cols 0-3 & 132-135
        int q = p - 1088;
        row = 4 + (q >> 3);
        int c = q & 7;
        px = (c < 4) ? c : c + 128;
    }
    float4* dst = (float4*)((char*)feats +
        ((((size_t)b * PH + row) * NCH + ch) * ROWE) * 2 + (size_t)swz(px, w) * 16);
    *dst = make_float4(0.f, 0.f, 0.f, 0.f);
}

// Scatter x into feats channel 0, chunk 0 (swizzled layout).
__global__ void init_x(const float* __restrict__ x, unsigned short* __restrict__ feats) {
    int idx = blockIdx.x * 256 + threadIdx.x;
    if (idx >= BATCH * HH * WW) return;
    int xw = idx & (WW - 1);
    int yy = (idx >> 7) & (HH - 1);
    int b  = idx >> 14;
    int pp = xw + 4;
    feats[((((size_t)b * PH + (yy + 4)) * NCH)) * ROWE + (size_t)swz(pp, 0) * 8]
        = f2bf(x[idx]);
}

// One dense block. wg = (b, 4-row strip), 4 waves x 32 px. Per step r the
// staged input row r serves all (o,ky) with o+ky==r: 4x B-frag reuse.
// A (weights) streams from global into a 4-deep ky register window; the
// retiring slot is refilled ONLY AFTER the MFMA loop (R7 bug: refilling
// before the loop clobbers slot (step-3)&3 still needed by o=3).
// B-READS: rounds 2-7 established the ds_read issue pipe is ~90% busy —
// 18 reads/step fetched 18 KB from a 3 KB window. Now each wave reads just
// P0,P1,P2 (3 contiguous ds_read_b128) and synthesizes the 16 shifted
// fragments on the VALU via DPP row shifts (mkfrag). LDS reads 18->3,
// trading ~1500 idle-free LDS cycles for ~770 VALU cycles per SIMD-step.
__global__ __launch_bounds__(256, 2) void block_kern(
    unsigned short* feats, const unsigned short* __restrict__ wbuf,
    const float* __restrict__ b1, const float* __restrict__ w2,
    const float* __restrict__ b2, float* __restrict__ out,
    int blk, int nchunk)
{
    __shared__ __align__(16) unsigned short sB[2][ROWP];

    // XCD-chunked decode: XCD (bid&7, round-robin dispatch) owns batches
    // 2x..2x+1 (feats slice 2.4 MB < 4 MB XCD L2). Bijective on [0,512).
    const int xcd = blockIdx.x & 7;
    const int i   = blockIdx.x >> 3;        // 0..63
    const int b   = 2 * xcd + (i >> 5);
    const int s   = i & 31;                 // 4-row strip 0..31

    const int tid  = threadIdx.x;
    const int lane = tid & 63;
    const int wv   = tid >> 6;
    const int n    = lane & 15;
    const int kg   = lane >> 4;
    const int x0   = wv * 32;

    floatx4 acc[4][2];
    #pragma unroll
    for (int o = 0; o < 4; ++o)
        #pragma unroll
        for (int t = 0; t < 2; ++t)
            acc[o][t] = (floatx4){0.f, 0.f, 0.f, 0.f};

    const unsigned short* fb = feats + (size_t)b * PH * NCH * ROWE;

    for (int c = 0; c < nchunk; ++c) {
        const unsigned short* wsrc = wbuf + (size_t)(blk * NCH + c) * 81 * TAPE + lane * 8;

        short8 Areg[4][9];
        // prologue: stage row 0, load ky=0 taps into the window
        stage_row(fb + (size_t)((4 * s) * NCH + c) * ROWE, &sB[0][0], tid);
        #pragma unroll
        for (int kx = 0; kx < 9; ++kx)
            Areg[0][kx] = *(const short8*)(wsrc + (size_t)kx * TAPE);
        __syncthreads();

        #pragma unroll
        for (int step = 0; step < 12; ++step) {
            if (step < 11)
                stage_row(fb + (size_t)((4 * s + step + 1) * NCH + c) * ROWE,
                          &sB[(step + 1) & 1][0], tid);

            const unsigned short* bb = &sB[step & 1][0];
            // The wave's 48-px strip, 3 reads. P2's lanes n>=8 may cover
            // pad/garbage px (wave 3: px 136-143) — those lanes are 0-masked
            // by mkfrag's shift select and never consumed.
            short8 P0 = *(const short8*)(bb + (size_t)swz(x0 + n,      kg) * 8);
            short8 P1 = *(const short8*)(bb + (size_t)swz(x0 + 16 + n, kg) * 8);
            short8 P2 = *(const short8*)(bb + (size_t)swz(x0 + 32 + n, kg) * 8);

#define DO_KX(KX)                                                              \
            {                                                                  \
                short8 B0 = mkfrag<KX>(P0, P1);                                \
                short8 B1 = mkfrag<KX>(P1, P2);                                \
                _Pragma("unroll")                                              \
                for (int o = 0; o < 4; ++o) {                                  \
                    if (o <= step && step - o <= 8) {                          \
                        acc[o][0] = __builtin_amdgcn_mfma_f32_16x16x32_bf16(   \
                            Areg[(step - o) & 3][KX], B0, acc[o][0], 0, 0, 0); \
                        acc[o][1] = __builtin_amdgcn_mfma_f32_16x16x32_bf16(   \
                            Areg[(step - o) & 3][KX], B1, acc[o][1], 0, 0, 0); \
                    }                                                          \
                }                                                              \
            }
            DO_KX(0) DO_KX(1) DO_KX(2) DO_KX(3) DO_KX(4)
            DO_KX(5) DO_KX(6) DO_KX(7) DO_KX(8)
#undef DO_KX

            // prefetch next ky's taps into the RETIRING window slot —
            // after the MFMA loop (slot (step+1)&3 == (step-3)&3 was
            // consumed by o=3 above).
            if (step < 8) {
                #pragma unroll
                for (int kx = 0; kx < 9; ++kx)
                    Areg[(step + 1) & 3][kx] =
                        *(const short8*)(wsrc + (size_t)((step + 1) * 9 + kx) * TAPE);
            }
            __syncthreads();
        }
    }

    // Epilogue: relu(h+b1)·w2, reduce 16 hidden, sigmoid, write out + feats.
    float b1v[4], w2v[4];
    #pragma unroll
    for (int r = 0; r < 4; ++r) {
        b1v[r] = b1[blk * HID + kg * 4 + r];
        w2v[r] = w2[blk * HID + kg * 4 + r];
    }
    const float bb2 = b2[blk];
    const int cw = blk + 1, cchunk = cw >> 5, cidx = cw & 31;

    #pragma unroll
    for (int o = 0; o < 4; ++o) {
        const int yrow = 4 * s + o;
        #pragma unroll
        for (int t = 0; t < 2; ++t) {
            float p = 0.f;
            #pragma unroll
            for (int r = 0; r < 4; ++r)
                p += fmaxf(acc[o][t][r] + b1v[r], 0.f) * w2v[r];
            p += __shfl_xor(p, 16, 64);
            p += __shfl_xor(p, 32, 64);
            if (kg == 0) {
                float yv = 1.f / (1.f + __expf(-(p + bb2)));
                int px = x0 + 16 * t + n;
                out[(((size_t)b * NBLK + blk) * HH + yrow) * WW + px] = yv;
                int pp = px + 4;
                feats[(((size_t)b * PH + (yrow + 4)) * NCH + cchunk) * ROWE
                      + (size_t)swz(pp, cidx >> 3) * 8 + (cidx & 7)] = f2bf(yv);
            }
        }
    }
}

extern "C" void kernel_launch(void* const* d_in, const int* in_sizes, int n_in,
                              void* d_out, int out_size, void* d_ws, size_t ws_size,
                              hipStream_t stream) {
    const float* x  = (const float*)d_in[0];
    const float* w1 = (const float*)d_in[1];
    const float* b1 = (const float*)d_in[2];
    const float* w2 = (const float*)d_in[3];
    const float* b2 = (const float*)d_in[4];
    float* out = (float*)d_out;

    unsigned short* feats = (unsigned short*)d_ws;
    size_t feats_bytes = (size_t)BATCH * PH * NCH * ROWE * sizeof(unsigned short); // ~37.9 MB
    unsigned short* wbuf = (unsigned short*)((char*)d_ws + feats_bytes);           // ~8.3 MB

    const int htotal = BATCH * NCH * 2112 * 4;
    zero_halo<<<(htotal + 255) / 256, 256, 0, stream>>>(feats);
    init_x<<<(BATCH * HH * WW + 255) / 256, 256, 0, stream>>>(x, feats);
    const int wtotal = NBLK * NCH * 81 * TAPE;
    prep_w<<<(wtotal + 255) / 256, 256, 0, stream>>>(w1, wbuf);

    for (int blk = 0; blk < NBLK; ++blk) {
        int nchunk = (blk + 32) / 32;  // ceil((blk+1)/32)
        block_kern<<<BATCH * 32, 256, 0, stream>>>(feats, wbuf, b1, w2, b2, out, blk, nchunk);
    }
}

// Round 9
// 1367.718 us; speedup vs baseline: 1.1086x; 1.1086x over previous
//
#include <hip/hip_runtime.h>
#include <hip/hip_bf16.h>

#define NBLK 50
#define HID  16
#define BATCH 16
#define HH 128
#define WW 128
#define PH 136
#define PW 136
#define NCH 2
#define PXS 32                 // shorts per pixel (64 B) in GLOBAL feats layout
#define ROWE (PW*PXS)          // 4352 shorts = 8704 B per (row, chunk)
#define TAPE 512               // elements per A tap-fragment (64 lanes * 8)

typedef __attribute__((ext_vector_type(8))) short short8;
typedef __attribute__((ext_vector_type(4))) float floatx4;

static __device__ __forceinline__ unsigned short f2bf(float f) {
    unsigned int u = __float_as_uint(f);
    unsigned int r = (u + 0x7fffu + ((u >> 16) & 1u)) >> 16;
    return (unsigned short)r;
}

// Unit swizzle (16B units), involutive within each 64-unit block:
//   uswz(v) = v ^ ((v>>3)&7);  uswz(uswz(v)) == v.
// Global feats layout stores pixel px's channel-unit kg at unit index
// uswz(4*px+kg) — identical to the verified R2 swizzle
// (4px+kg)^((px>>1)&7). Bank-conflict-free for the wave's B reads.
static __device__ __forceinline__ int uswz(int v) { return v ^ ((v >> 3) & 7); }
static __device__ __forceinline__ int swz(int px, int kg) { return uswz(px * 4 + kg); }

#define GLD16(gp, lp) __builtin_amdgcn_global_load_lds( \
    (__attribute__((address_space(1))) void*)(void*)(gp), \
    (__attribute__((address_space(3))) void*)(lp), 16, 0, 0)

// COMPACT STAGE: copy only the first U=2^sh channel-units of each pixel
// (the live ones for this chunk) into LDS. NU = 136*U units total.
// LDS slot j holds unit v = uswz(j) (involution => read side uses uswz too;
// for U=4 source degenerates to linear j*16 — byte-identical to R2's
// full-row stage). Source gather uses gld_lds's per-lane GLOBAL addressing;
// LDS dest stays linear (wave-uniform base + lane*16), per m104 semantics.
static __device__ __forceinline__ void stage_row_u(
    const unsigned short* g, unsigned short* l, int tid,
    int NU, int sh, int um1) {
    #pragma unroll
    for (int t = 0; t < 3; ++t) {
        int j = t * 256 + tid;
        if (j < NU) {
            int v  = uswz(j);                       // unit stored at slot j
            int pg = ((v >> sh) << 2) + (v & um1);  // global 4*px+un
            GLD16((const char*)g + (size_t)uswz(pg) * 16,
                  (char*)l + (size_t)(t * 256 + (tid & ~63)) * 16);
        }
    }
}

// Pack w1 (fp32 [50][16][51][9][9]) into A-fragment order:
// wbuf[blk][chunk][tap][lane][8], lane: m=lane&15 (hidden ch), k=(lane>>4)*8+j.
// Zero for c>blk (K-padding + write-channel read-safety).
__global__ void prep_w(const float* __restrict__ w1, unsigned short* __restrict__ wbuf) {
    int idx = blockIdx.x * 256 + threadIdx.x;
    const int total = NBLK * NCH * 81 * TAPE;
    if (idx >= total) return;
    int e    = idx & 7;
    int lane = (idx >> 3) & 63;
    int tap  = (idx >> 9) % 81;
    int bc   = idx / (81 * TAPE);
    int ch   = bc & 1, blk = bc >> 1;
    int hc   = lane & 15;
    int c    = ch * 32 + (lane >> 4) * 8 + e;
    float v = 0.f;
    if (c <= blk) v = w1[(((size_t)blk * HID + hc) * (1 + NBLK) + c) * 81 + tap];
    wbuf[idx] = f2bf(v);
}

// Zero only the halo pixels (swizzled unit addresses). Unwritten interior
// channels are safe: weight columns zeroed in wbuf, 0xAA-poison bf16 finite.
__global__ void zero_halo(unsigned short* __restrict__ feats) {
    int t = blockIdx.x * 256 + threadIdx.x;
    const int PPX = 2112;                 // halo px per (b, chunk)
    const int TOT = BATCH * NCH * PPX * 4;
    if (t >= TOT) return;
    int w    = t & 3;
    int rest = t >> 2;
    int p    = rest % PPX;
    int ch   = (rest / PPX) % NCH;
    int b    = rest / (PPX * NCH);
    int row, px;
    if (p < 1088) {                        // rows 0-3, 132-135 (full)
        int r4 = p / 136; px = p % 136;
        row = (r4 < 4) ? r4 : r4 + 128;
    } else {                               // rows 4-131, cols 0-3 & 132-135
        int q = p - 1088;
        row = 4 + (q >> 3);
        int c = q & 7;
        px = (c < 4) ? c : c + 128;
    }
    float4* dst = (float4*)((char*)feats +
        ((((size_t)b * PH + row) * NCH + ch) * ROWE) * 2 + (size_t)swz(px, w) * 16);
    *dst = make_float4(0.f, 0.f, 0.f, 0.f);
}

// Scatter x into feats channel 0, chunk 0 (swizzled layout).
__global__ void init_x(const float* __restrict__ x, unsigned short* __restrict__ feats) {
    int idx = blockIdx.x * 256 + threadIdx.x;
    if (idx >= BATCH * HH * WW) return;
    int xw = idx & (WW - 1);
    int yy = (idx >> 7) & (HH - 1);
    int b  = idx >> 14;
    int pp = xw + 4;
    feats[((((size_t)b * PH + (yy + 4)) * NCH)) * ROWE + (size_t)swz(pp, 0) * 8]
        = f2bf(x[idx]);
}

// One dense block. wg = (b, 4-row strip), 4 waves x 32 px. Per step r the
// staged input row r serves all (o,ky) with o+ky==r: 4x B-frag reuse.
// A (weights) streams from global into a 4-deep ky register window; the
// retiring slot is refilled only AFTER the MFMA loop. LDS carries only B
// rows, conflict-free-swizzled.
// COMPACT STAGING (this round): chunk c has Kc=min(blk+1-32c,32) live
// channels = kgs k-groups; stage only U = {1,2,4} units/px (kgs=3 -> 4).
// Cuts stage HBM bytes 4x/2x on 32 of 69 chunk-passes and shrinks the
// per-XCD t2 working set to ~3-3.6 MB < 4 MB XCD-L2, so stages become
// L2 hits (R8 established LDS/barriers/banks are all non-binding; the
// residual is HBM-latency staging — FETCH_SIZE 53 MB == full re-fetch).
// Dead kg lanes (kg>=U) broadcast-read unit kg&(U-1): weights zeroed.
__global__ __launch_bounds__(256, 2) void block_kern(
    unsigned short* feats, const unsigned short* __restrict__ wbuf,
    const float* __restrict__ b1, const float* __restrict__ w2,
    const float* __restrict__ b2, float* __restrict__ out,
    int blk, int nchunk)
{
    __shared__ __align__(16) unsigned short sB[2][ROWE];

    // XCD-chunked decode: XCD (bid&7, round-robin dispatch) owns batches
    // 2x..2x+1; adjacent strips' shared halo rows become same-XCD L2 hits.
    // Bijective on [0,512).
    const int xcd = blockIdx.x & 7;
    const int i   = blockIdx.x >> 3;        // 0..63
    const int b   = 2 * xcd + (i >> 5);
    const int s   = i & 31;                 // 4-row strip 0..31

    const int tid  = threadIdx.x;
    const int lane = tid & 63;
    const int wv   = tid >> 6;
    const int n    = lane & 15;
    const int kg   = lane >> 4;
    const int x0   = wv * 32;

    floatx4 acc[4][2];
    #pragma unroll
    for (int o = 0; o < 4; ++o)
        #pragma unroll
        for (int t = 0; t < 2; ++t)
            acc[o][t] = (floatx4){0.f, 0.f, 0.f, 0.f};

    const unsigned short* fb = feats + (size_t)b * PH * NCH * ROWE;

    for (int c = 0; c < nchunk; ++c) {
        const unsigned short* wsrc = wbuf + (size_t)(blk * NCH + c) * 81 * TAPE + lane * 8;

        // chunk's live-unit count U = 2^sh (kgs=3 rounds to 4)
        int Kc = blk + 1 - 32 * c;
        if (Kc > 32) Kc = 32;
        const int kgs = (Kc + 7) >> 3;              // 1..4
        const int sh  = (kgs >= 3) ? 2 : (kgs >> 1); // 1->0, 2->1, 3/4->2
        const int um1 = (1 << sh) - 1;
        const int NU  = 136 << sh;                   // units per staged row
        const int bvx = ((x0 + n) << sh) + (kg & um1); // lane's base unit idx

        short8 Areg[4][9];
        // prologue: stage row 0, load ky=0 taps into the window
        stage_row_u(fb + (size_t)((4 * s) * NCH + c) * ROWE, &sB[0][0], tid,
                    NU, sh, um1);
        #pragma unroll
        for (int kx = 0; kx < 9; ++kx)
            Areg[0][kx] = *(const short8*)(wsrc + (size_t)kx * TAPE);
        __syncthreads();

        #pragma unroll
        for (int step = 0; step < 12; ++step) {
            if (step < 11)
                stage_row_u(fb + (size_t)((4 * s + step + 1) * NCH + c) * ROWE,
                            &sB[(step + 1) & 1][0], tid, NU, sh, um1);

            const unsigned short* bb = &sB[step & 1][0];
            #pragma unroll
            for (int kx = 0; kx < 9; ++kx) {
                const int v0 = bvx + (kx << sh);
                const int v1 = bvx + ((16 + kx) << sh);
                short8 B0 = *(const short8*)(bb + (size_t)uswz(v0) * 8);
                short8 B1 = *(const short8*)(bb + (size_t)uswz(v1) * 8);
                #pragma unroll
                for (int o = 0; o < 4; ++o) {
                    if (o <= step && step - o <= 8) {
                        acc[o][0] = __builtin_amdgcn_mfma_f32_16x16x32_bf16(
                            Areg[(step - o) & 3][kx], B0, acc[o][0], 0, 0, 0);
                        acc[o][1] = __builtin_amdgcn_mfma_f32_16x16x32_bf16(
                            Areg[(step - o) & 3][kx], B1, acc[o][1], 0, 0, 0);
                    }
                }
            }

            // prefetch next ky's taps into the retiring window slot
            if (step < 8) {
                #pragma unroll
                for (int kx = 0; kx < 9; ++kx)
                    Areg[(step + 1) & 3][kx] =
                        *(const short8*)(wsrc + (size_t)((step + 1) * 9 + kx) * TAPE);
            }
            __syncthreads();
        }
    }

    // Epilogue: relu(h+b1)·w2, reduce 16 hidden, sigmoid, write out + feats.
    float b1v[4], w2v[4];
    #pragma unroll
    for (int r = 0; r < 4; ++r) {
        b1v[r] = b1[blk * HID + kg * 4 + r];
        w2v[r] = w2[blk * HID + kg * 4 + r];
    }
    const float bb2 = b2[blk];
    const int cw = blk + 1, cchunk = cw >> 5, cidx = cw & 31;

    #pragma unroll
    for (int o = 0; o < 4; ++o) {
        const int yrow = 4 * s + o;
        #pragma unroll
        for (int t = 0; t < 2; ++t) {
            float p = 0.f;
            #pragma unroll
            for (int r = 0; r < 4; ++r)
                p += fmaxf(acc[o][t][r] + b1v[r], 0.f) * w2v[r];
            p += __shfl_xor(p, 16, 64);
            p += __shfl_xor(p, 32, 64);
            if (kg == 0) {
                float yv = 1.f / (1.f + __expf(-(p + bb2)));
                int px = x0 + 16 * t + n;
                out[(((size_t)b * NBLK + blk) * HH + yrow) * WW + px] = yv;
                int pp = px + 4;
                feats[(((size_t)b * PH + (yrow + 4)) * NCH + cchunk) * ROWE
                      + (size_t)swz(pp, cidx >> 3) * 8 + (cidx & 7)] = f2bf(yv);
            }
        }
    }
}

extern "C" void kernel_launch(void* const* d_in, const int* in_sizes, int n_in,
                              void* d_out, int out_size, void* d_ws, size_t ws_size,
                              hipStream_t stream) {
    const float* x  = (const float*)d_in[0];
    const float* w1 = (const float*)d_in[1];
    const float* b1 = (const float*)d_in[2];
    const float* w2 = (const float*)d_in[3];
    const float* b2 = (const float*)d_in[4];
    float* out = (float*)d_out;

    unsigned short* feats = (unsigned short*)d_ws;
    size_t feats_bytes = (size_t)BATCH * PH * NCH * ROWE * sizeof(unsigned short); // ~37.9 MB
    unsigned short* wbuf = (unsigned short*)((char*)d_ws + feats_bytes);           // ~8.3 MB

    const int htotal = BATCH * NCH * 2112 * 4;
    zero_halo<<<(htotal + 255) / 256, 256, 0, stream>>>(feats);
    init_x<<<(BATCH * HH * WW + 255) / 256, 256, 0, stream>>>(x, feats);
    const int wtotal = NBLK * NCH * 81 * TAPE;
    prep_w<<<(wtotal + 255) / 256, 256, 0, stream>>>(w1, wbuf);

    for (int blk = 0; blk < NBLK; ++blk) {
        int nchunk = (blk + 32) / 32;  // ceil((blk+1)/32)
        block_kern<<<BATCH * 32, 256, 0, stream>>>(feats, wbuf, b1, w2, b2, out, blk, nchunk);
    }
}

// Round 11
// 1169.551 us; speedup vs baseline: 1.2965x; 1.1694x over previous
//
#include <hip/hip_runtime.h>
#include <hip/hip_bf16.h>

#define NBLK 50
#define HID  16
#define BATCH 16
#define HH 128
#define WW 128
#define PH 136
#define PW 136
#define NCH 2
#define PXS 32                 // shorts per pixel (64 B) in GLOBAL feats layout
#define ROWE (PW*PXS)          // 4352 shorts = 8704 B per (row, chunk)
#define TAPE 512               // elements per A tap-fragment (64 lanes * 8)

typedef __attribute__((ext_vector_type(8))) short short8;
typedef __attribute__((ext_vector_type(4))) float floatx4;

static __device__ __forceinline__ unsigned short f2bf(float f) {
    unsigned int u = __float_as_uint(f);
    unsigned int r = (u + 0x7fffu + ((u >> 16) & 1u)) >> 16;
    return (unsigned short)r;
}

// Unit swizzle (16B units), involutive within each 64-unit block:
//   uswz(v) = v ^ ((v>>3)&7);  uswz(uswz(v)) == v.
// Global feats layout stores pixel px's channel-unit kg at unit index
// uswz(4*px+kg). Bank-conflict-free for the wave's B reads.
static __device__ __forceinline__ int uswz(int v) { return v ^ ((v >> 3) & 7); }
static __device__ __forceinline__ int swz(int px, int kg) { return uswz(px * 4 + kg); }

#define GLD16(gp, lp) __builtin_amdgcn_global_load_lds( \
    (__attribute__((address_space(1))) void*)(void*)(gp), \
    (__attribute__((address_space(3))) void*)(lp), 16, 0, 0)

// COMPACT STAGE (verified R9): copy only the first U=2^sh channel-units of
// each pixel into LDS; slot j holds unit uswz(j) (involution; U=4 source
// degenerates to linear — byte-identical to the R2 full-row stage).
static __device__ __forceinline__ void stage_row_u(
    const unsigned short* g, unsigned short* l, int tid,
    int NU, int sh, int um1) {
    #pragma unroll
    for (int t = 0; t < 3; ++t) {
        int j = t * 256 + tid;
        if (j < NU) {
            int v  = uswz(j);                       // unit stored at slot j
            int pg = ((v >> sh) << 2) + (v & um1);  // global 4*px+un
            GLD16((const char*)g + (size_t)uswz(pg) * 16,
                  (char*)l + (size_t)(t * 256 + (tid & ~63)) * 16);
        }
    }
}

// Pack w1 (fp32 [50][16][51][9][9]) into K-PACKED A-fragment order.
// For a chunk with kgs live k-groups (U=2^sh units), P=4/U kx-taps share
// one MFMA: k = kg*8+j maps to tap kx = q*P + (kg>>sh), channel
// c_local = (kg&um1)*8 + j. Slot index = ky*9 + q (q < PT, rest zeroed).
// sh=2 (kgs>=3) reproduces the original layout exactly (kx=q, c_local=kg*8+j).
// Zero for dead taps (kx>8) and dead channels (c>blk) — read-safety.
__global__ void prep_w(const float* __restrict__ w1, unsigned short* __restrict__ wbuf) {
    int idx = blockIdx.x * 256 + threadIdx.x;
    const int total = NBLK * NCH * 81 * TAPE;
    if (idx >= total) return;
    int e    = idx & 7;
    int lane = (idx >> 3) & 63;
    int slot = (idx >> 9) % 81;
    int bc   = idx / (81 * TAPE);
    int ch   = bc & 1, blk = bc >> 1;
    int hc   = lane & 15, kg = lane >> 4;
    int Kc = blk + 1 - 32 * ch;
    if (Kc > 32) Kc = 32;
    float v = 0.f;
    if (Kc >= 1) {
        int kgs = (Kc + 7) >> 3;
        int sh  = (kgs >= 3) ? 2 : (kgs >> 1);      // 1->0, 2->1, 3/4->2
        int P   = 4 >> sh;
        int ky  = slot / 9, q = slot % 9;
        int kx  = q * P + (kg >> sh);
        int cl  = (kg & ((1 << sh) - 1)) * 8 + e;
        int c   = ch * 32 + cl;
        if (kx <= 8 && c <= blk)
            v = w1[(((size_t)blk * HID + hc) * (1 + NBLK) + c) * 81 + ky * 9 + kx];
    }
    wbuf[idx] = f2bf(v);
}

// Zero only the halo pixels (swizzled unit addresses). Unwritten interior
// channels are safe: weight columns zeroed in wbuf, 0xAA-poison bf16 finite.
__global__ void zero_halo(unsigned short* __restrict__ feats) {
    int t = blockIdx.x * 256 + threadIdx.x;
    const int PPX = 2112;                 // halo px per (b, chunk)
    const int TOT = BATCH * NCH * PPX * 4;
    if (t >= TOT) return;
    int w    = t & 3;
    int rest = t >> 2;
    int p    = rest % PPX;
    int ch   = (rest / PPX) % NCH;
    int b    = rest / (PPX * NCH);
    int row, px;
    if (p < 1088) {                        // rows 0-3, 132-135 (full)
        int r4 = p / 136; px = p % 136;
        row = (r4 < 4) ? r4 : r4 + 128;
    } else {                               // rows 4-131, cols 0-3 & 132-135
        int q = p - 1088;
        row = 4 + (q >> 3);
        int c = q & 7;
        px = (c < 4) ? c : c + 128;
    }
    float4* dst = (float4*)((char*)feats +
        ((((size_t)b * PH + row) * NCH + ch) * ROWE) * 2 + (size_t)swz(px, w) * 16);
    *dst = make_float4(0.f, 0.f, 0.f, 0.f);
}

// Scatter x into feats channel 0, chunk 0 (swizzled layout).
__global__ void init_x(const float* __restrict__ x, unsigned short* __restrict__ feats) {
    int idx = blockIdx.x * 256 + threadIdx.x;
    if (idx >= BATCH * HH * WW) return;
    int xw = idx & (WW - 1);
    int yy = (idx >> 7) & (HH - 1);
    int b  = idx >> 14;
    int pp = xw + 4;
    feats[((((size_t)b * PH + (yy + 4)) * NCH)) * ROWE + (size_t)swz(pp, 0) * 8]
        = f2bf(x[idx]);
}

// One chunk of one dense block, K-PACKED (template SH = log2 units/px):
// SH=2: P=1, PT=9 — byte-identical to the verified R2/R9 path.
// SH=1: P=2, PT=5 — taps (2q, 2q+1) share one MFMA (kg 0,1 -> tap 2q
//        channels 0-15; kg 2,3 -> tap 2q+1 channels 0-15).
// SH=0: P=4, PT=3 — taps 4q..4q+3 share one MFMA (kg -> tap 4q+kg, ch 0-7).
// B unit index: v = (px + q*P + (kg>>SH))*U + (kg&um1); q advances v by 4
// regardless of SH (P*U==4). MFMA count per (o,t,step): 9 -> PT.
// Dead-tap fragments (kx>8) have zeroed A columns; their B reads can land
// up to 7 units past NU — those guard slots are zero-filled per chunk so
// 0 x garbage can never be 0 x NaN.
template<int SH>
static __device__ __forceinline__ void chunk_pass(
    const unsigned short* __restrict__ base,    // fb + (4s*NCH + c)*ROWE
    const unsigned short* __restrict__ wsrc,    // wbuf(blk,c) + lane*8
    unsigned short (*sB)[ROWE],
    floatx4 (&acc)[4][2],
    int tid, int n, int kg, int x0)
{
    constexpr int P   = 4 >> SH;          // taps packed per MFMA
    constexpr int PT  = (8 + P) / P;      // packed-tap count: 9, 5, 3
    constexpr int um1 = (1 << SH) - 1;
    constexpr int NU  = 136 << SH;        // staged units per row
    const int bvx = ((x0 + n + (kg >> SH)) << SH) + (kg & um1);
    const size_t rstride = (size_t)NCH * ROWE;

    // guard slots: zero units NU..NU+7 of BOTH buffers (dead-tap overreads
    // stay within these; SH=2 has no dead taps).
    if constexpr (SH < 2) {
        if (tid < 16)
            *(short8*)(&sB[tid >> 3][(size_t)(NU + (tid & 7)) * 8]) =
                (short8){0, 0, 0, 0, 0, 0, 0, 0};
    }

    short8 Areg[4][PT];
    // prologue: stage row 0, load ky=0 packed taps
    stage_row_u(base, &sB[0][0], tid, NU, SH, um1);
    #pragma unroll
    for (int q = 0; q < PT; ++q)
        Areg[0][q] = *(const short8*)(wsrc + (size_t)q * TAPE);
    __syncthreads();

    #pragma unroll
    for (int step = 0; step < 12; ++step) {
        if (step < 11)
            stage_row_u(base + (size_t)(step + 1) * rstride,
                        &sB[(step + 1) & 1][0], tid, NU, SH, um1);

        const unsigned short* bb = &sB[step & 1][0];
        #pragma unroll
        for (int q = 0; q < PT; ++q) {
            short8 B0 = *(const short8*)(bb + (size_t)uswz(bvx + 4 * q) * 8);
            short8 B1 = *(const short8*)(bb + (size_t)uswz(bvx + (16 << SH) + 4 * q) * 8);
            #pragma unroll
            for (int o = 0; o < 4; ++o) {
                if (o <= step && step - o <= 8) {
                    acc[o][0] = __builtin_amdgcn_mfma_f32_16x16x32_bf16(
                        Areg[(step - o) & 3][q], B0, acc[o][0], 0, 0, 0);
                    acc[o][1] = __builtin_amdgcn_mfma_f32_16x16x32_bf16(
                        Areg[(step - o) & 3][q], B1, acc[o][1], 0, 0, 0);
                }
            }
        }

        // refill the RETIRING window slot only AFTER the MFMA loop
        if (step < 8) {
            #pragma unroll
            for (int q = 0; q < PT; ++q)
                Areg[(step + 1) & 3][q] =
                    *(const short8*)(wsrc + (size_t)((step + 1) * 9 + q) * TAPE);
        }
        __syncthreads();
    }
}

// wg = (b, 4-row strip), 4 waves x 32 px; diagonal o+ky==step, 4-deep A
// window (all verified R2 structure). Per-chunk K-packing via chunk_pass<SH>.
__global__ __launch_bounds__(256, 2) void block_kern(
    unsigned short* feats, const unsigned short* __restrict__ wbuf,
    const float* __restrict__ b1, const float* __restrict__ w2,
    const float* __restrict__ b2, float* __restrict__ out,
    int blk, int nchunk)
{
    __shared__ __align__(16) unsigned short sB[2][ROWE];

    // XCD-chunked decode: XCD (bid&7) owns batches 2x..2x+1. Bijective.
    const int xcd = blockIdx.x & 7;
    const int i   = blockIdx.x >> 3;        // 0..63
    const int b   = 2 * xcd + (i >> 5);
    const int s   = i & 31;                 // 4-row strip 0..31

    const int tid  = threadIdx.x;
    const int lane = tid & 63;
    const int wv   = tid >> 6;
    const int n    = lane & 15;
    const int kg   = lane >> 4;
    const int x0   = wv * 32;

    floatx4 acc[4][2];
    #pragma unroll
    for (int o = 0; o < 4; ++o)
        #pragma unroll
        for (int t = 0; t < 2; ++t)
            acc[o][t] = (floatx4){0.f, 0.f, 0.f, 0.f};

    const unsigned short* fb = feats + (size_t)b * PH * NCH * ROWE;

    for (int c = 0; c < nchunk; ++c) {
        const unsigned short* wsrc = wbuf + (size_t)(blk * NCH + c) * 81 * TAPE + lane * 8;
        const unsigned short* base = fb + (size_t)((4 * s) * NCH + c) * ROWE;
        int Kc = blk + 1 - 32 * c;
        if (Kc > 32) Kc = 32;
        const int kgs = (Kc + 7) >> 3;      // 1..4 (wg-uniform)
        if (kgs >= 3)      chunk_pass<2>(base, wsrc, sB, acc, tid, n, kg, x0);
        else if (kgs == 2) chunk_pass<1>(base, wsrc, sB, acc, tid, n, kg, x0);
        else               chunk_pass<0>(base, wsrc, sB, acc, tid, n, kg, x0);
    }

    // Epilogue: relu(h+b1)·w2, reduce 16 hidden, sigmoid, write out + feats.
    float b1v[4], w2v[4];
    #pragma unroll
    for (int r = 0; r < 4; ++r) {
        b1v[r] = b1[blk * HID + kg * 4 + r];
        w2v[r] = w2[blk * HID + kg * 4 + r];
    }
    const float bb2 = b2[blk];
    const int cw = blk + 1, cchunk = cw >> 5, cidx = cw & 31;

    #pragma unroll
    for (int o = 0; o < 4; ++o) {
        const int yrow = 4 * s + o;
        #pragma unroll
        for (int t = 0; t < 2; ++t) {
            float p = 0.f;
            #pragma unroll
            for (int r = 0; r < 4; ++r)
                p += fmaxf(acc[o][t][r] + b1v[r], 0.f) * w2v[r];
            p += __shfl_xor(p, 16, 64);
            p += __shfl_xor(p, 32, 64);
            if (kg == 0) {
                float yv = 1.f / (1.f + __expf(-(p + bb2)));
                int px = x0 + 16 * t + n;
                out[(((size_t)b * NBLK + blk) * HH + yrow) * WW + px] = yv;
                int pp = px + 4;
                feats[(((size_t)b * PH + (yrow + 4)) * NCH + cchunk) * ROWE
                      + (size_t)swz(pp, cidx >> 3) * 8 + (cidx & 7)] = f2bf(yv);
            }
        }
    }
}

extern "C" void kernel_launch(void* const* d_in, const int* in_sizes, int n_in,
                              void* d_out, int out_size, void* d_ws, size_t ws_size,
                              hipStream_t stream) {
    const float* x  = (const float*)d_in[0];
    const float* w1 = (const float*)d_in[1];
    const float* b1 = (const float*)d_in[2];
    const float* w2 = (const float*)d_in[3];
    const float* b2 = (const float*)d_in[4];
    float* out = (float*)d_out;

    unsigned short* feats = (unsigned short*)d_ws;
    size_t feats_bytes = (size_t)BATCH * PH * NCH * ROWE * sizeof(unsigned short); // ~37.9 MB
    unsigned short* wbuf = (unsigned short*)((char*)d_ws + feats_bytes);           // ~8.3 MB

    const int htotal = BATCH * NCH * 2112 * 4;
    zero_halo<<<(htotal + 255) / 256, 256, 0, stream>>>(feats);
    init_x<<<(BATCH * HH * WW + 255) / 256, 256, 0, stream>>>(x, feats);
    const int wtotal = NBLK * NCH * 81 * TAPE;
    prep_w<<<(wtotal + 255) / 256, 256, 0, stream>>>(w1, wbuf);

    for (int blk = 0; blk < NBLK; ++blk) {
        int nchunk = (blk + 32) / 32;  // ceil((blk+1)/32)
        block_kern<<<BATCH * 32, 256, 0, stream>>>(feats, wbuf, b1, w2, b2, out, blk, nchunk);
    }
}